// Round 4
// baseline (166.084 us; speedup 1.0000x reference)
//
#include <hip/hip_runtime.h>
#include <hip/hip_bf16.h>
#include <stdint.h>

#define SDEP 128
#define NRES 256
#define CZQ 128

typedef __bf16 v8bf __attribute__((ext_vector_type(8)));
typedef __bf16 v4bf __attribute__((ext_vector_type(4)));
typedef float v16f __attribute__((ext_vector_type(16)));
typedef float v4f __attribute__((ext_vector_type(4)));

// full-wave sum via DPP (VALU pipe, no LDS). Result valid in lane 63.
__device__ __forceinline__ float dpp_wave_sum(float x) {
  float t;
#define STEP(ctrl)                                                         \
  t = __builtin_bit_cast(float, __builtin_amdgcn_update_dpp(               \
          0, __builtin_bit_cast(int, x), ctrl, 0xF, 0xF, true));           \
  x += t;
  STEP(0x111)  // row_shr:1
  STEP(0x112)  // row_shr:2
  STEP(0x114)  // row_shr:4
  STEP(0x118)  // row_shr:8
  STEP(0x142)  // row_bcast15
  STEP(0x143)  // row_bcast31 -> lane63 = sum(0..63)
#undef STEP
  return x;
}
__device__ __forceinline__ float lane63(float x) {
  return __builtin_bit_cast(float,
      __builtin_amdgcn_readlane(__builtin_bit_cast(int, x), 63));
}

// ---------------- Kernel A: fused prep + LN + projections ------------
// blocks 0..255   : LN+proj for i=bid (wcat built per-block in LDS)
// blocks 256..511 : rnorm row (bid-256)
// blocks 512..543 : wot3 transpose
__global__ __launch_bounds__(256, 1) void fusedA_kernel(
    const float* __restrict__ msa, const float* __restrict__ lnw,
    const float* __restrict__ lnb, const float* __restrict__ wl,
    const float* __restrict__ wr, const float* __restrict__ mask,
    const float* __restrict__ wo, const float* __restrict__ bl,
    const float* __restrict__ br,
    __bf16* __restrict__ At2, __bf16* __restrict__ Bt2,
    float* __restrict__ rnorm, __bf16* __restrict__ wot3)
{
  __shared__ __bf16 xs[128 * 258];
  __shared__ __bf16 Ls[4 * 64 * 36];
  __shared__ __bf16 wcs[16384];

  const int bid = blockIdx.x, t = threadIdx.x;
  if (bid >= 256) {
    if (bid < 512) {
      const int b = bid - 256;
      float acc = 0.f;
      for (int s = 0; s < SDEP; ++s)
        acc += mask[s * NRES + b] * mask[s * NRES + t];
      rnorm[b * NRES + t] = 1.f / fmaxf(acc, 1.f);
    } else {
      const int base = (bid - 512) * 4096 + t;
      #pragma unroll
      for (int u = 0; u < 16; ++u) {
        int idx = base + u * 256;
        int q = idx & 31, n = (idx >> 5) & 15, kk = (idx >> 9) & 31, wv = idx >> 14;
        wot3[idx] = (__bf16)wo[(kk * 32 + q) * CZQ + wv * 16 + n];
      }
    }
    return;
  }

  const int i = bid;
  const int w = t >> 6, lane = t & 63;
  const int half = lane >> 5, l31 = lane & 31;

  // ---- build wcat in LDS: wcs[((tile*16+ks)*2+half)*256 + n*8+j] ----
  #pragma unroll
  for (int u = 0; u < 64; ++u) {
    int idx = u * 256 + t;
    int j = idx & 7, n = (idx >> 3) & 31, hf = (idx >> 8) & 1;
    int ks = (idx >> 9) & 15, tile = idx >> 13;
    const float* wsrc = tile ? wr : wl;
    wcs[idx] = (__bf16)wsrc[(ks * 16 + hf * 8 + j) * 32 + n];
  }

  const float4 wv4 = ((const float4*)lnw)[lane];
  const float4 bv4 = ((const float4*)lnb)[lane];

  // ---- Phase 1: LN of this wave's 32 rows into LDS (wave-private) ----
  #pragma unroll 8
  for (int r = 0; r < 32; ++r) {
    const int s = w * 32 + r;
    float4 x = ((const float4*)(msa + ((size_t)s * 256 + i) * 256))[lane];
    float s1 = dpp_wave_sum(x.x + x.y + x.z + x.w);
    float s2 = dpp_wave_sum(x.x * x.x + x.y * x.y + x.z * x.z + x.w * x.w);
    float mu = lane63(s1) * (1.f / 256.f);
    float var = lane63(s2) * (1.f / 256.f) - mu * mu;
    float rs = rsqrtf(var + 1e-5f);
    v4bf o;
    o[0] = (__bf16)((x.x - mu) * rs * wv4.x + bv4.x);
    o[1] = (__bf16)((x.y - mu) * rs * wv4.y + bv4.y);
    o[2] = (__bf16)((x.z - mu) * rs * wv4.z + bv4.z);
    o[3] = (__bf16)((x.w - mu) * rs * wv4.w + bv4.w);
    *(v4bf*)(xs + s * 258 + lane * 4) = o;
  }
  __syncthreads();   // wcs shared across waves

  // ---- Phase 2: [32 s-rows x 256k] @ wcs -> acc (MFMA) ----
  v16f acc0, acc1;
  #pragma unroll
  for (int r = 0; r < 16; ++r) { acc0[r] = 0.f; acc1[r] = 0.f; }

  const __bf16* xrow = xs + (w * 32 + l31) * 258 + half * 8;
  const __bf16* bbase = wcs + half * 256 + l31 * 8;
  #pragma unroll
  for (int ks = 0; ks < 16; ++ks) {
    v8bf a  = *(const v8bf*)(xrow + ks * 16);
    v8bf b0 = *(const v8bf*)(bbase + ks * 512);
    v8bf b1 = *(const v8bf*)(bbase + 8192 + ks * 512);
    acc0 = __builtin_amdgcn_mfma_f32_32x32x16_bf16(a, b0, acc0, 0, 0, 0);
    acc1 = __builtin_amdgcn_mfma_f32_32x32x16_bf16(a, b1, acc1, 0, 0, 0);
  }

  // ---- Epilogue: bias+mask, transpose via wave-private LDS tile ----
  __bf16* Lw = Ls + w * 64 * 36;
  const float bA = bl[l31], bB = br[l31];
  #pragma unroll
  for (int r = 0; r < 16; ++r) {
    int sl = (r & 3) + 8 * (r >> 2) + 4 * half;
    float mv = mask[(w * 32 + sl) * NRES + i];
    Lw[l31 * 36 + sl]        = (__bf16)((acc0[r] + bA) * mv);
    Lw[(32 + l31) * 36 + sl] = (__bf16)((acc1[r] + bB) * mv);
  }

  const int c = lane >> 1, jq = (lane & 1) * 4;
  #pragma unroll
  for (int o = 0; o < 4; ++o) {
    int oct = w * 4 + o;
    v4bf va = *(const v4bf*)(Lw + c * 36 + o * 8 + jq);
    v4bf vb = *(const v4bf*)(Lw + (32 + c) * 36 + o * 8 + jq);
    *(v4bf*)(At2 + ((size_t)i * 16 + oct) * 256 + lane * 4) = va;
    *(v4bf*)(Bt2 + ((size_t)i * 16 + oct) * 256 + lane * 4) = vb;
  }
}

// ---------------- Kernel B: fused outer-product-mean + out proj ------
// tile 128x512 = (4 i) x (16 j), grid (16 j-tiles, 64 i-tiles) x 1024 thr
__global__ __launch_bounds__(1024, 4) void outer_kernel(
    const __bf16* __restrict__ At2, const __bf16* __restrict__ Bt2,
    const float* __restrict__ rnorm, const __bf16* __restrict__ wot3,
    const float* __restrict__ bo, float* __restrict__ out)
{
  __shared__ __bf16 Ps[64 * 1032];
  const int tid = threadIdx.x;
  const int w = tid >> 6, lane = tid & 63;
  const int half = lane >> 5, l31 = lane & 31;
  const int bx = blockIdx.x;  // 16 j's
  const int by = blockIdx.y;  // 4 i's
  const int mt = w >> 3;      // i-pair (0..1)
  const int nt = w & 7;       // j-pair (0..7)

  const __bf16* Ap = At2 + ((size_t)(by * 4 + mt * 2)) * 4096 + l31 * 8;
  const __bf16* Bp = Bt2 + ((size_t)(bx * 16 + nt * 2)) * 4096 + l31 * 8;

  v16f acc[2][2];
  #pragma unroll
  for (int a = 0; a < 2; ++a)
    #pragma unroll
    for (int b = 0; b < 2; ++b)
      #pragma unroll
      for (int r = 0; r < 16; ++r) acc[a][b][r] = 0.f;

  #pragma unroll
  for (int ks = 0; ks < 8; ++ks) {
    int off = (ks * 2 + half) * 256;
    v8bf a0 = *(const v8bf*)(Ap + off);
    v8bf a1 = *(const v8bf*)(Ap + 4096 + off);
    v8bf b0 = *(const v8bf*)(Bp + off);
    v8bf b1 = *(const v8bf*)(Bp + 4096 + off);
    acc[0][0] = __builtin_amdgcn_mfma_f32_32x32x16_bf16(a0, b0, acc[0][0], 0, 0, 0);
    acc[0][1] = __builtin_amdgcn_mfma_f32_32x32x16_bf16(a0, b1, acc[0][1], 0, 0, 0);
    acc[1][0] = __builtin_amdgcn_mfma_f32_32x32x16_bf16(a1, b0, acc[1][0], 0, 0, 0);
    acc[1][1] = __builtin_amdgcn_mfma_f32_32x32x16_bf16(a1, b1, acc[1][1], 0, 0, 0);
  }

  // P[p][c*32+d], p = i_local*16 + j_local
  #pragma unroll
  for (int ti = 0; ti < 2; ++ti) {
    #pragma unroll
    for (int tj = 0; tj < 2; ++tj) {
      int il = mt * 2 + ti, jl = nt * 2 + tj;
      int p = il * 16 + jl;
      float rn = rnorm[(by * 4 + il) * NRES + bx * 16 + jl];
      #pragma unroll
      for (int r = 0; r < 16; ++r) {
        int cc = (r & 3) + 8 * (r >> 2) + 4 * half;
        Ps[p * 1032 + cc * 32 + l31] = (__bf16)(acc[ti][tj][r] * rn);
      }
    }
  }
  __syncthreads();

  // GEMM2: [64 x 1024] @ wot3 -> [64 x 128]
  // wave w: z-slice (w&7)*16, m-tiles {(w>>3)*2, (w>>3)*2+1}
  const int mr = lane & 15, kq = lane >> 4;
  const int zw = w & 7;
  const int mbase = (w >> 3) * 2;
  const int z = zw * 16 + mr;
  const __bf16* wp = wot3 + (size_t)zw * 16384 + mr * 32 + kq * 8;
  const __bf16* pA = Ps + (mbase * 16 + mr) * 1032 + kq * 8;
  v4f acc2[2];
  #pragma unroll
  for (int t = 0; t < 2; ++t)
    #pragma unroll
    for (int r = 0; r < 4; ++r) acc2[t][r] = 0.f;

  #pragma unroll 8
  for (int kk = 0; kk < 32; ++kk) {
    v8bf b  = *(const v8bf*)(wp + kk * 512);
    v8bf a0 = *(const v8bf*)(pA + kk * 32);
    v8bf a1 = *(const v8bf*)(pA + 16 * 1032 + kk * 32);
    acc2[0] = __builtin_amdgcn_mfma_f32_16x16x32_bf16(a0, b, acc2[0], 0, 0, 0);
    acc2[1] = __builtin_amdgcn_mfma_f32_16x16x32_bf16(a1, b, acc2[1], 0, 0, 0);
  }

  const float bz = bo[z];
  #pragma unroll
  for (int t2 = 0; t2 < 2; ++t2) {
    #pragma unroll
    for (int r = 0; r < 4; ++r) {
      int p = (mbase + t2) * 16 + kq * 4 + r;
      int i = by * 4 + (p >> 4), j = bx * 16 + (p & 15);
      out[((size_t)i * NRES + j) * CZQ + z] = acc2[t2][r] + bz;
    }
  }
}

extern "C" void kernel_launch(void* const* d_in, const int* in_sizes, int n_in,
                              void* d_out, int out_size, void* d_ws, size_t ws_size,
                              hipStream_t stream) {
  const float* msa  = (const float*)d_in[0];
  const float* mask = (const float*)d_in[1];
  const float* lnw  = (const float*)d_in[2];
  const float* lnb  = (const float*)d_in[3];
  const float* wl   = (const float*)d_in[4];
  const float* bl   = (const float*)d_in[5];
  const float* wr   = (const float*)d_in[6];
  const float* br   = (const float*)d_in[7];
  const float* wo   = (const float*)d_in[8];
  const float* bo   = (const float*)d_in[9];
  float* out = (float*)d_out;

  char* ws = (char*)d_ws;
  __bf16* At2   = (__bf16*)(ws);                    // 2 MB
  __bf16* Bt2   = (__bf16*)(ws + 2097152);          // 2 MB
  float*  rnorm = (float*)(ws + 4194304);           // 256 KB
  __bf16* wot3  = (__bf16*)(ws + 4456448);          // 256 KB

  fusedA_kernel<<<544, 256, 0, stream>>>(msa, lnw, lnb, wl, wr, mask, wo,
                                         bl, br, At2, Bt2, rnorm, wot3);
  outer_kernel<<<dim3(16, 64), 1024, 0, stream>>>(At2, Bt2, rnorm, wot3, bo, out);
}

// Round 5
// 155.846 us; speedup vs baseline: 1.0657x; 1.0657x over previous
//
#include <hip/hip_runtime.h>
#include <hip/hip_bf16.h>
#include <stdint.h>

#define SDEP 128
#define NRES 256
#define CZQ 128

typedef __bf16 v8bf __attribute__((ext_vector_type(8)));
typedef __bf16 v4bf __attribute__((ext_vector_type(4)));
typedef float v16f __attribute__((ext_vector_type(16)));

// full-wave sum via DPP (VALU pipe, no LDS). Result valid in lane 63.
__device__ __forceinline__ float dpp_wave_sum(float x) {
  float t;
#define STEP(ctrl)                                                         \
  t = __builtin_bit_cast(float, __builtin_amdgcn_update_dpp(               \
          0, __builtin_bit_cast(int, x), ctrl, 0xF, 0xF, true));           \
  x += t;
  STEP(0x111)
  STEP(0x112)
  STEP(0x114)
  STEP(0x118)
  STEP(0x142)
  STEP(0x143)
#undef STEP
  return x;
}
__device__ __forceinline__ float lane63(float x) {
  return __builtin_bit_cast(float,
      __builtin_amdgcn_readlane(__builtin_bit_cast(int, x), 63));
}

// ---------------- Kernel A: fused prep + LN + projections ------------
// 256 blocks x 512 thr, exactly 1 block/CU, 1 round.
// Block i: LN + proj for residue i. Wave w: s-block sb=w>>1, n-half nh=w&1.
// Blocks 0..127 also build rnorm rows {2i,2i+1}; 128..255 build wot4 chunk.
__global__ __launch_bounds__(512, 2) void fusedA_kernel(
    const float* __restrict__ msa, const float* __restrict__ lnw,
    const float* __restrict__ lnb, const float* __restrict__ wl,
    const float* __restrict__ wr, const float* __restrict__ mask,
    const float* __restrict__ wo, const float* __restrict__ bl,
    const float* __restrict__ br,
    __bf16* __restrict__ At2, __bf16* __restrict__ Bt2,
    float* __restrict__ rnorm, __bf16* __restrict__ wot4)
{
  __shared__ __bf16 xs[128 * 258];      // 66 KB
  __shared__ __bf16 wcs[16384];         // 32 KB
  __shared__ __bf16 Ls[8 * 32 * 36];    // 18 KB

  const int i = blockIdx.x, t = threadIdx.x;
  const int w = t >> 6, lane = t & 63;
  const int half = lane >> 5, l31 = lane & 31;
  const int sb = w >> 1, nh = w & 1;

  // ---- build wcat in LDS: wcs[((nh*16+ks)*2+half)*256 + n*8+j] ----
  #pragma unroll
  for (int u = 0; u < 32; ++u) {
    int idx = u * 512 + t;
    int j = idx & 7, n = (idx >> 3) & 31, hf = (idx >> 8) & 1;
    int ks = (idx >> 9) & 15, tile = idx >> 13;
    const float* wsrc = tile ? wr : wl;
    wcs[idx] = (__bf16)wsrc[(ks * 16 + hf * 8 + j) * 32 + n];
  }

  const float4 wv4 = ((const float4*)lnw)[lane];
  const float4 bv4 = ((const float4*)lnb)[lane];

  // ---- LN: wave w handles rows sb*32 + nh*16 + (0..15) ----
  #pragma unroll 8
  for (int r = 0; r < 16; ++r) {
    const int s = sb * 32 + nh * 16 + r;
    float4 x = ((const float4*)(msa + ((size_t)s * 256 + i) * 256))[lane];
    float s1 = dpp_wave_sum(x.x + x.y + x.z + x.w);
    float s2 = dpp_wave_sum(x.x * x.x + x.y * x.y + x.z * x.z + x.w * x.w);
    float mu = lane63(s1) * (1.f / 256.f);
    float var = lane63(s2) * (1.f / 256.f) - mu * mu;
    float rs = rsqrtf(var + 1e-5f);
    v4bf o;
    o[0] = (__bf16)((x.x - mu) * rs * wv4.x + bv4.x);
    o[1] = (__bf16)((x.y - mu) * rs * wv4.y + bv4.y);
    o[2] = (__bf16)((x.z - mu) * rs * wv4.z + bv4.z);
    o[3] = (__bf16)((x.w - mu) * rs * wv4.w + bv4.w);
    *(v4bf*)(xs + s * 258 + lane * 4) = o;
  }
  __syncthreads();   // xs shared within wave pair; wcs shared by all

  // ---- MFMA: [32 s-rows of sb] x [n-half nh], 16 ks ----
  v16f acc;
  #pragma unroll
  for (int r = 0; r < 16; ++r) acc[r] = 0.f;

  const __bf16* xrow = xs + (sb * 32 + l31) * 258 + half * 8;
  const __bf16* bbase = wcs + nh * 8192 + half * 256 + l31 * 8;
  #pragma unroll
  for (int ks = 0; ks < 16; ++ks) {
    v8bf a = *(const v8bf*)(xrow + ks * 16);
    v8bf b = *(const v8bf*)(bbase + ks * 512);
    acc = __builtin_amdgcn_mfma_f32_32x32x16_bf16(a, b, acc, 0, 0, 0);
  }

  // ---- epilogue: bias+mask, transpose via wave-private LDS tile ----
  __bf16* Lw = Ls + w * 32 * 36;
  const float bias = (nh ? br : bl)[l31];
  #pragma unroll
  for (int r = 0; r < 16; ++r) {
    int sl = (r & 3) + 8 * (r >> 2) + 4 * half;   // s_local in sb block
    float mv = mask[(sb * 32 + sl) * NRES + i];
    Lw[l31 * 36 + sl] = (__bf16)((acc[r] + bias) * mv);
  }

  __bf16* dst = nh ? Bt2 : At2;
  const int c = lane >> 1, jq = (lane & 1) * 4;
  #pragma unroll
  for (int o = 0; o < 4; ++o) {
    v4bf v = *(const v4bf*)(Lw + c * 36 + o * 8 + jq);
    *(v4bf*)(dst + ((size_t)i * 16 + sb * 4 + o) * 256 + lane * 4) = v;
  }

  // ---- aux tails ----
  if (i < 128) {
    // rnorm rows 2i, 2i+1
    const int b = i * 2 + (t >> 8), col = t & 255;
    float a0 = 0.f;
    #pragma unroll 4
    for (int s = 0; s < SDEP; ++s)
      a0 += mask[s * NRES + b] * mask[s * NRES + col];
    rnorm[b * NRES + col] = 1.f / fmaxf(a0, 1.f);
  } else {
    // wot4[(((zg*64 + kk)*64) + half*32 + l31)*8 + j] = wo[k][z]
    #pragma unroll
    for (int u = 0; u < 2; ++u) {
      int idx = (i - 128) * 1024 + u * 512 + t;
      int j = idx & 7, lc = (idx >> 3) & 63, kk = (idx >> 9) & 63, zg = idx >> 15;
      int k = kk * 16 + (lc >> 5) * 8 + j;
      int z = zg * 32 + (lc & 31);
      wot4[idx] = (__bf16)wo[k * CZQ + z];
    }
  }
}

// ---------------- Kernel B: fused outer-product-mean + out proj ------
// tile 128x256 = (4 i) x (8 j), grid (32,64) x 512 thr, 66KB LDS, 2 blk/CU
__global__ __launch_bounds__(512, 4) void outer_kernel(
    const __bf16* __restrict__ At2, const __bf16* __restrict__ Bt2,
    const float* __restrict__ rnorm, const __bf16* __restrict__ wot4,
    const float* __restrict__ bo, float* __restrict__ out)
{
  __shared__ char smem[66048];
  __bf16* Ps = (__bf16*)smem;          // [32 p][1032]
  float* red = (float*)smem;           // reused for pair reduction

  const int tid = threadIdx.x;
  const int w = tid >> 6, lane = tid & 63;
  const int half = lane >> 5, l31 = lane & 31;
  const int bx = blockIdx.x;  // 8 j's
  const int by = blockIdx.y;  // 4 i's
  const int mt = w >> 1;      // i-local 0..3
  const int nh = w & 1;       // j half

  // ---- GEMM1: direct-global fragment loads ----
  const __bf16* Ap = At2 + ((size_t)(by * 4 + mt)) * 4096 + l31 * 8;
  const __bf16* Bp = Bt2 + ((size_t)(bx * 8 + nh * 4)) * 4096 + l31 * 8;

  v16f acc[4];
  #pragma unroll
  for (int t = 0; t < 4; ++t)
    #pragma unroll
    for (int r = 0; r < 16; ++r) acc[t][r] = 0.f;

  #pragma unroll
  for (int ks = 0; ks < 8; ++ks) {
    int off = (ks * 2 + half) * 256;
    v8bf a = *(const v8bf*)(Ap + off);
    #pragma unroll
    for (int t = 0; t < 4; ++t) {
      v8bf b = *(const v8bf*)(Bp + t * 4096 + off);
      acc[t] = __builtin_amdgcn_mfma_f32_32x32x16_bf16(a, b, acc[t], 0, 0, 0);
    }
  }

  // ---- P[p][c*32+d] = outer * rnorm, p = mt*8 + jl ----
  #pragma unroll
  for (int t = 0; t < 4; ++t) {
    int jl = nh * 4 + t;
    int p = mt * 8 + jl;
    float rn = rnorm[(by * 4 + mt) * NRES + bx * 8 + jl];
    #pragma unroll
    for (int r = 0; r < 16; ++r) {
      int cc = (r & 3) + 8 * (r >> 2) + 4 * half;
      Ps[p * 1032 + cc * 32 + l31] = (__bf16)(acc[t][r] * rn);
    }
  }
  __syncthreads();

  // ---- GEMM2: 32x32x16 MFMA, K-split across wave pairs ----
  // wave (zg = w&3, kh = w>>2): z cols zg*32..+31, k = (kh*32+kk)*16..
  const int zg = w & 3, kh = w >> 2;
  const __bf16* wp = wot4 + ((size_t)((zg * 64 + kh * 32) * 64) + half * 32 + l31) * 8;
  const __bf16* pp = Ps + l31 * 1032 + kh * 512 + half * 8;

  v16f c2;
  #pragma unroll
  for (int r = 0; r < 16; ++r) c2[r] = 0.f;

  #pragma unroll 4
  for (int kk = 0; kk < 32; ++kk) {
    v8bf a = *(const v8bf*)(pp + kk * 16);
    v8bf b = *(const v8bf*)(wp + kk * 512);
    c2 = __builtin_amdgcn_mfma_f32_32x32x16_bf16(a, b, c2, 0, 0, 0);
  }
  __syncthreads();   // all Ps reads done; reuse LDS for reduction

  if (kh == 1) {
    #pragma unroll
    for (int r = 0; r < 16; ++r) {
      int cc = (r & 3) + 8 * (r >> 2) + 4 * half;
      red[zg * 1024 + cc * 32 + l31] = c2[r];
    }
  }
  __syncthreads();

  if (kh == 0) {
    const float bz = bo[zg * 32 + l31];
    #pragma unroll
    for (int r = 0; r < 16; ++r) {
      int cc = (r & 3) + 8 * (r >> 2) + 4 * half;   // = p row
      float v = c2[r] + red[zg * 1024 + cc * 32 + l31] + bz;
      int i = by * 4 + (cc >> 3), j = bx * 8 + (cc & 7);
      out[((size_t)i * NRES + j) * CZQ + zg * 32 + l31] = v;
    }
  }
}

extern "C" void kernel_launch(void* const* d_in, const int* in_sizes, int n_in,
                              void* d_out, int out_size, void* d_ws, size_t ws_size,
                              hipStream_t stream) {
  const float* msa  = (const float*)d_in[0];
  const float* mask = (const float*)d_in[1];
  const float* lnw  = (const float*)d_in[2];
  const float* lnb  = (const float*)d_in[3];
  const float* wl   = (const float*)d_in[4];
  const float* bl   = (const float*)d_in[5];
  const float* wr   = (const float*)d_in[6];
  const float* br   = (const float*)d_in[7];
  const float* wo   = (const float*)d_in[8];
  const float* bo   = (const float*)d_in[9];
  float* out = (float*)d_out;

  char* ws = (char*)d_ws;
  __bf16* At2   = (__bf16*)(ws);                    // 2 MB
  __bf16* Bt2   = (__bf16*)(ws + 2097152);          // 2 MB
  float*  rnorm = (float*)(ws + 4194304);           // 256 KB
  __bf16* wot4  = (__bf16*)(ws + 4456448);          // 256 KB

  fusedA_kernel<<<256, 512, 0, stream>>>(msa, lnw, lnb, wl, wr, mask, wo,
                                         bl, br, At2, Bt2, rnorm, wot4);
  outer_kernel<<<dim3(32, 64), 512, 0, stream>>>(At2, Bt2, rnorm, wot4, bo, out);
}

// Round 6
// 153.409 us; speedup vs baseline: 1.0826x; 1.0159x over previous
//
#include <hip/hip_runtime.h>
#include <hip/hip_bf16.h>
#include <stdint.h>

#define SDEP 128
#define NRES 256
#define CZQ 128

typedef __bf16 v8bf __attribute__((ext_vector_type(8)));
typedef __bf16 v4bf __attribute__((ext_vector_type(4)));
typedef float v16f __attribute__((ext_vector_type(16)));

// full-wave sum via DPP (VALU pipe, no LDS). Result valid in lane 63.
__device__ __forceinline__ float dpp_wave_sum(float x) {
  float t;
#define STEP(ctrl)                                                         \
  t = __builtin_bit_cast(float, __builtin_amdgcn_update_dpp(               \
          0, __builtin_bit_cast(int, x), ctrl, 0xF, 0xF, true));           \
  x += t;
  STEP(0x111)
  STEP(0x112)
  STEP(0x114)
  STEP(0x118)
  STEP(0x142)
  STEP(0x143)
#undef STEP
  return x;
}
__device__ __forceinline__ float lane63(float x) {
  return __builtin_bit_cast(float,
      __builtin_amdgcn_readlane(__builtin_bit_cast(int, x), 63));
}

// ---------------- Kernel A: fused prep + LN + projections ------------
// 256 blocks x 512 thr, 1 block/CU, 1 round.
__global__ __launch_bounds__(512, 2) void fusedA_kernel(
    const float* __restrict__ msa, const float* __restrict__ lnw,
    const float* __restrict__ lnb, const float* __restrict__ wl,
    const float* __restrict__ wr, const float* __restrict__ mask,
    const float* __restrict__ wo, const float* __restrict__ bl,
    const float* __restrict__ br,
    __bf16* __restrict__ At2, __bf16* __restrict__ Bt2,
    float* __restrict__ rnorm, __bf16* __restrict__ wot4)
{
  __shared__ __bf16 xs[128 * 258];      // 66 KB
  __shared__ __bf16 wcs[16384];         // 32 KB
  __shared__ __bf16 Ls[8 * 32 * 36];    // 18 KB

  const int i = blockIdx.x, t = threadIdx.x;
  const int w = t >> 6, lane = t & 63;
  const int half = lane >> 5, l31 = lane & 31;
  const int sb = w >> 1, nh = w & 1;

  // ---- build wcat in LDS: wcs[((nh*16+ks)*2+half)*256 + n*8+j] ----
  #pragma unroll
  for (int u = 0; u < 32; ++u) {
    int idx = u * 512 + t;
    int j = idx & 7, n = (idx >> 3) & 31, hf = (idx >> 8) & 1;
    int ks = (idx >> 9) & 15, tile = idx >> 13;
    const float* wsrc = tile ? wr : wl;
    wcs[idx] = (__bf16)wsrc[(ks * 16 + hf * 8 + j) * 32 + n];
  }

  const float4 wv4 = ((const float4*)lnw)[lane];
  const float4 bv4 = ((const float4*)lnb)[lane];

  // ---- LN: wave w handles rows sb*32 + nh*16 + (0..15) ----
  #pragma unroll 8
  for (int r = 0; r < 16; ++r) {
    const int s = sb * 32 + nh * 16 + r;
    float4 x = ((const float4*)(msa + ((size_t)s * 256 + i) * 256))[lane];
    float s1 = dpp_wave_sum(x.x + x.y + x.z + x.w);
    float s2 = dpp_wave_sum(x.x * x.x + x.y * x.y + x.z * x.z + x.w * x.w);
    float mu = lane63(s1) * (1.f / 256.f);
    float var = lane63(s2) * (1.f / 256.f) - mu * mu;
    float rs = rsqrtf(var + 1e-5f);
    v4bf o;
    o[0] = (__bf16)((x.x - mu) * rs * wv4.x + bv4.x);
    o[1] = (__bf16)((x.y - mu) * rs * wv4.y + bv4.y);
    o[2] = (__bf16)((x.z - mu) * rs * wv4.z + bv4.z);
    o[3] = (__bf16)((x.w - mu) * rs * wv4.w + bv4.w);
    *(v4bf*)(xs + s * 258 + lane * 4) = o;
  }
  __syncthreads();

  // ---- MFMA: [32 s-rows of sb] x [n-half nh], 16 ks ----
  v16f acc;
  #pragma unroll
  for (int r = 0; r < 16; ++r) acc[r] = 0.f;

  const __bf16* xrow = xs + (sb * 32 + l31) * 258 + half * 8;
  const __bf16* bbase = wcs + nh * 8192 + half * 256 + l31 * 8;
  #pragma unroll
  for (int ks = 0; ks < 16; ++ks) {
    v8bf a = *(const v8bf*)(xrow + ks * 16);
    v8bf b = *(const v8bf*)(bbase + ks * 512);
    acc = __builtin_amdgcn_mfma_f32_32x32x16_bf16(a, b, acc, 0, 0, 0);
  }

  // ---- epilogue: bias+mask, transpose via wave-private LDS tile ----
  __bf16* Lw = Ls + w * 32 * 36;
  const float bias = (nh ? br : bl)[l31];
  #pragma unroll
  for (int r = 0; r < 16; ++r) {
    int sl = (r & 3) + 8 * (r >> 2) + 4 * half;
    float mv = mask[(sb * 32 + sl) * NRES + i];
    Lw[l31 * 36 + sl] = (__bf16)((acc[r] + bias) * mv);
  }

  __bf16* dst = nh ? Bt2 : At2;
  const int c = lane >> 1, jq = (lane & 1) * 4;
  #pragma unroll
  for (int o = 0; o < 4; ++o) {
    v4bf v = *(const v4bf*)(Lw + c * 36 + o * 8 + jq);
    *(v4bf*)(dst + ((size_t)i * 16 + sb * 4 + o) * 256 + lane * 4) = v;
  }

  // ---- aux tails ----
  if (i < 128) {
    const int b = i * 2 + (t >> 8), col = t & 255;
    float a0 = 0.f;
    #pragma unroll 4
    for (int s = 0; s < SDEP; ++s)
      a0 += mask[s * NRES + b] * mask[s * NRES + col];
    rnorm[b * NRES + col] = 1.f / fmaxf(a0, 1.f);
  } else {
    #pragma unroll
    for (int u = 0; u < 2; ++u) {
      int idx = (i - 128) * 1024 + u * 512 + t;
      int j = idx & 7, lc = (idx >> 3) & 63, kk = (idx >> 9) & 63, zg = idx >> 15;
      int k = kk * 16 + (lc >> 5) * 8 + j;
      int z = zg * 32 + (lc & 31);
      wot4[idx] = (__bf16)wo[k * CZQ + z];
    }
  }
}

// ---------------- Kernel B: fused outer-product-mean + out proj ------
// tile 128x256 = (4 i) x (8 j), grid (32,64) x 512 thr, 66KB LDS, 2 blk/CU
__global__ __launch_bounds__(512, 4) void outer_kernel(
    const __bf16* __restrict__ At2, const __bf16* __restrict__ Bt2,
    const float* __restrict__ rnorm, const __bf16* __restrict__ wot4,
    const float* __restrict__ bo, float* __restrict__ out)
{
  __shared__ char smem[66048];
  __bf16* Ps = (__bf16*)smem;          // [32 p][1032]
  float* red = (float*)smem;           // reused for pair reduction

  const int tid = threadIdx.x;
  const int w = tid >> 6, lane = tid & 63;
  const int half = lane >> 5, l31 = lane & 31;
  const int bx = blockIdx.x;  // 8 j's
  const int by = blockIdx.y;  // 4 i's
  const int mt = w >> 1;      // i-local 0..3
  const int nh = w & 1;       // j half

  // ---- GEMM1: direct-global fragment loads, deep MLP ----
  const __bf16* Ap = At2 + ((size_t)(by * 4 + mt)) * 4096 + l31 * 8;
  const __bf16* Bp = Bt2 + ((size_t)(bx * 8 + nh * 4)) * 4096 + l31 * 8;

  // preload all 8 A-fragments (independent, in flight together)
  v8bf a[8];
  #pragma unroll
  for (int ks = 0; ks < 8; ++ks)
    a[ks] = *(const v8bf*)(Ap + (ks * 2 + half) * 256);

  v16f acc[4];
  #pragma unroll
  for (int t = 0; t < 4; ++t)
    #pragma unroll
    for (int r = 0; r < 16; ++r) acc[t][r] = 0.f;

  #pragma unroll
  for (int t = 0; t < 4; ++t) {
    v8bf b[8];
    #pragma unroll
    for (int ks = 0; ks < 8; ++ks)
      b[ks] = *(const v8bf*)(Bp + t * 4096 + (ks * 2 + half) * 256);
    #pragma unroll
    for (int ks = 0; ks < 8; ++ks)
      acc[t] = __builtin_amdgcn_mfma_f32_32x32x16_bf16(a[ks], b[ks], acc[t], 0, 0, 0);
  }

  // ---- P[p][c*32+d] = outer * rnorm, p = mt*8 + jl ----
  #pragma unroll
  for (int t = 0; t < 4; ++t) {
    int jl = nh * 4 + t;
    int p = mt * 8 + jl;
    float rn = rnorm[(by * 4 + mt) * NRES + bx * 8 + jl];
    #pragma unroll
    for (int r = 0; r < 16; ++r) {
      int cc = (r & 3) + 8 * (r >> 2) + 4 * half;
      Ps[p * 1032 + cc * 32 + l31] = (__bf16)(acc[t][r] * rn);
    }
  }

  // ---- GEMM2 wot prefetch: issue BEFORE the barrier (flies during it) ----
  const int zg = w & 3, kh = w >> 2;
  const __bf16* wp = wot4 + ((size_t)((zg * 64 + kh * 32) * 64) + half * 32 + l31) * 8;
  v8bf wb[8];
  #pragma unroll
  for (int u = 0; u < 8; ++u)
    wb[u] = *(const v8bf*)(wp + u * 512);

  __syncthreads();

  // ---- GEMM2: 32x32x16 MFMA, K-split across wave pairs, rolling wb ----
  const __bf16* pp = Ps + l31 * 1032 + kh * 512 + half * 8;

  v16f c2;
  #pragma unroll
  for (int r = 0; r < 16; ++r) c2[r] = 0.f;

  #pragma unroll
  for (int g = 0; g < 4; ++g) {
    #pragma unroll
    for (int u = 0; u < 8; ++u) {
      const int kk = g * 8 + u;
      v8bf bb = wb[u];
      if (g < 3) wb[u] = *(const v8bf*)(wp + (kk + 8) * 512);
      v8bf aa = *(const v8bf*)(pp + kk * 16);
      c2 = __builtin_amdgcn_mfma_f32_32x32x16_bf16(aa, bb, c2, 0, 0, 0);
    }
  }
  __syncthreads();   // all Ps reads done; reuse LDS for reduction

  if (kh == 1) {
    #pragma unroll
    for (int r = 0; r < 16; ++r) {
      int cc = (r & 3) + 8 * (r >> 2) + 4 * half;
      red[zg * 1024 + cc * 32 + l31] = c2[r];
    }
  }
  __syncthreads();

  if (kh == 0) {
    const float bz = bo[zg * 32 + l31];
    #pragma unroll
    for (int r = 0; r < 16; ++r) {
      int cc = (r & 3) + 8 * (r >> 2) + 4 * half;   // = p row
      float v = c2[r] + red[zg * 1024 + cc * 32 + l31] + bz;
      int i = by * 4 + (cc >> 3), j = bx * 8 + (cc & 7);
      out[((size_t)i * NRES + j) * CZQ + zg * 32 + l31] = v;
    }
  }
}

extern "C" void kernel_launch(void* const* d_in, const int* in_sizes, int n_in,
                              void* d_out, int out_size, void* d_ws, size_t ws_size,
                              hipStream_t stream) {
  const float* msa  = (const float*)d_in[0];
  const float* mask = (const float*)d_in[1];
  const float* lnw  = (const float*)d_in[2];
  const float* lnb  = (const float*)d_in[3];
  const float* wl   = (const float*)d_in[4];
  const float* bl   = (const float*)d_in[5];
  const float* wr   = (const float*)d_in[6];
  const float* br   = (const float*)d_in[7];
  const float* wo   = (const float*)d_in[8];
  const float* bo   = (const float*)d_in[9];
  float* out = (float*)d_out;

  char* ws = (char*)d_ws;
  __bf16* At2   = (__bf16*)(ws);                    // 2 MB
  __bf16* Bt2   = (__bf16*)(ws + 2097152);          // 2 MB
  float*  rnorm = (float*)(ws + 4194304);           // 256 KB
  __bf16* wot4  = (__bf16*)(ws + 4456448);          // 256 KB

  fusedA_kernel<<<256, 512, 0, stream>>>(msa, lnw, lnb, wl, wr, mask, wo,
                                         bl, br, At2, Bt2, rnorm, wot4);
  outer_kernel<<<dim3(32, 64), 512, 0, stream>>>(At2, Bt2, rnorm, wot4, bo, out);
}

// Round 7
// 151.687 us; speedup vs baseline: 1.0949x; 1.0114x over previous
//
#include <hip/hip_runtime.h>
#include <hip/hip_bf16.h>
#include <stdint.h>

#define SDEP 128
#define NRES 256
#define CZQ 128

typedef __bf16 v8bf __attribute__((ext_vector_type(8)));
typedef __bf16 v4bf __attribute__((ext_vector_type(4)));
typedef float v16f __attribute__((ext_vector_type(16)));

// full-wave sum via DPP (VALU pipe, no LDS). Result valid in lane 63.
__device__ __forceinline__ float dpp_wave_sum(float x) {
  float t;
#define STEP(ctrl)                                                         \
  t = __builtin_bit_cast(float, __builtin_amdgcn_update_dpp(               \
          0, __builtin_bit_cast(int, x), ctrl, 0xF, 0xF, true));           \
  x += t;
  STEP(0x111)
  STEP(0x112)
  STEP(0x114)
  STEP(0x118)
  STEP(0x142)
  STEP(0x143)
#undef STEP
  return x;
}
__device__ __forceinline__ float lane63(float x) {
  return __builtin_bit_cast(float,
      __builtin_amdgcn_readlane(__builtin_bit_cast(int, x), 63));
}

// ---------------- Kernel A: fused prep + LN + projections ------------
// 256 blocks x 512 thr, 1 block/CU, 1 round. (unchanged from R6)
__global__ __launch_bounds__(512, 2) void fusedA_kernel(
    const float* __restrict__ msa, const float* __restrict__ lnw,
    const float* __restrict__ lnb, const float* __restrict__ wl,
    const float* __restrict__ wr, const float* __restrict__ mask,
    const float* __restrict__ wo, const float* __restrict__ bl,
    const float* __restrict__ br,
    __bf16* __restrict__ At2, __bf16* __restrict__ Bt2,
    float* __restrict__ rnorm, __bf16* __restrict__ wot4)
{
  __shared__ __bf16 xs[128 * 258];      // 66 KB
  __shared__ __bf16 wcs[16384];         // 32 KB
  __shared__ __bf16 Ls[8 * 32 * 36];    // 18 KB

  const int i = blockIdx.x, t = threadIdx.x;
  const int w = t >> 6, lane = t & 63;
  const int half = lane >> 5, l31 = lane & 31;
  const int sb = w >> 1, nh = w & 1;

  #pragma unroll
  for (int u = 0; u < 32; ++u) {
    int idx = u * 512 + t;
    int j = idx & 7, n = (idx >> 3) & 31, hf = (idx >> 8) & 1;
    int ks = (idx >> 9) & 15, tile = idx >> 13;
    const float* wsrc = tile ? wr : wl;
    wcs[idx] = (__bf16)wsrc[(ks * 16 + hf * 8 + j) * 32 + n];
  }

  const float4 wv4 = ((const float4*)lnw)[lane];
  const float4 bv4 = ((const float4*)lnb)[lane];

  #pragma unroll 8
  for (int r = 0; r < 16; ++r) {
    const int s = sb * 32 + nh * 16 + r;
    float4 x = ((const float4*)(msa + ((size_t)s * 256 + i) * 256))[lane];
    float s1 = dpp_wave_sum(x.x + x.y + x.z + x.w);
    float s2 = dpp_wave_sum(x.x * x.x + x.y * x.y + x.z * x.z + x.w * x.w);
    float mu = lane63(s1) * (1.f / 256.f);
    float var = lane63(s2) * (1.f / 256.f) - mu * mu;
    float rs = rsqrtf(var + 1e-5f);
    v4bf o;
    o[0] = (__bf16)((x.x - mu) * rs * wv4.x + bv4.x);
    o[1] = (__bf16)((x.y - mu) * rs * wv4.y + bv4.y);
    o[2] = (__bf16)((x.z - mu) * rs * wv4.z + bv4.z);
    o[3] = (__bf16)((x.w - mu) * rs * wv4.w + bv4.w);
    *(v4bf*)(xs + s * 258 + lane * 4) = o;
  }
  __syncthreads();

  v16f acc;
  #pragma unroll
  for (int r = 0; r < 16; ++r) acc[r] = 0.f;

  const __bf16* xrow = xs + (sb * 32 + l31) * 258 + half * 8;
  const __bf16* bbase = wcs + nh * 8192 + half * 256 + l31 * 8;
  #pragma unroll
  for (int ks = 0; ks < 16; ++ks) {
    v8bf a = *(const v8bf*)(xrow + ks * 16);
    v8bf b = *(const v8bf*)(bbase + ks * 512);
    acc = __builtin_amdgcn_mfma_f32_32x32x16_bf16(a, b, acc, 0, 0, 0);
  }

  __bf16* Lw = Ls + w * 32 * 36;
  const float bias = (nh ? br : bl)[l31];
  #pragma unroll
  for (int r = 0; r < 16; ++r) {
    int sl = (r & 3) + 8 * (r >> 2) + 4 * half;
    float mv = mask[(sb * 32 + sl) * NRES + i];
    Lw[l31 * 36 + sl] = (__bf16)((acc[r] + bias) * mv);
  }

  __bf16* dst = nh ? Bt2 : At2;
  const int c = lane >> 1, jq = (lane & 1) * 4;
  #pragma unroll
  for (int o = 0; o < 4; ++o) {
    v4bf v = *(const v4bf*)(Lw + c * 36 + o * 8 + jq);
    *(v4bf*)(dst + ((size_t)i * 16 + sb * 4 + o) * 256 + lane * 4) = v;
  }

  if (i < 128) {
    const int b = i * 2 + (t >> 8), col = t & 255;
    float a0 = 0.f;
    #pragma unroll 4
    for (int s = 0; s < SDEP; ++s)
      a0 += mask[s * NRES + b] * mask[s * NRES + col];
    rnorm[b * NRES + col] = 1.f / fmaxf(a0, 1.f);
  } else {
    #pragma unroll
    for (int u = 0; u < 2; ++u) {
      int idx = (i - 128) * 1024 + u * 512 + t;
      int j = idx & 7, lc = (idx >> 3) & 63, kk = (idx >> 9) & 63, zg = idx >> 15;
      int k = kk * 16 + (lc >> 5) * 8 + j;
      int z = zg * 32 + (lc & 31);
      wot4[idx] = (__bf16)wo[k * CZQ + z];
    }
  }
}

// ---------------- Kernel B: fused outer-product-mean + out proj ------
// tile 128x256 = (4 i) x (8 j), grid (32,64) x 512 thr, 74KB LDS, 2 blk/CU
// G1 partition: wave (mh,nq) owns 64x64 quadrant (2 i-tiles x 2 j-tiles)
//   -> A+B L2 traffic 256 KB/block (was 320).
// G2 K-split partials stored bf16 in separate region -> one barrier fewer.
__global__ __launch_bounds__(512, 4) void outer_kernel(
    const __bf16* __restrict__ At2, const __bf16* __restrict__ Bt2,
    const float* __restrict__ rnorm, const __bf16* __restrict__ wot4,
    const float* __restrict__ bo, float* __restrict__ out)
{
  __shared__ char smem[74240];
  __bf16* Ps   = (__bf16*)smem;            // [32 p][1032]
  __bf16* redb = (__bf16*)(smem + 66048);  // [4 zg][1024] bf16 partials

  const int tid = threadIdx.x;
  const int w = tid >> 6, lane = tid & 63;
  const int half = lane >> 5, l31 = lane & 31;
  const int bx = blockIdx.x;  // 8 j's
  const int by = blockIdx.y;  // 4 i's
  const int mh = w >> 2;      // i-pair (0..1)
  const int nq = w & 3;       // j-pair (0..3)

  // ---- GEMM1: 64x64 quadrant per wave ----
  const __bf16* Ap = At2 + ((size_t)(by * 4 + mh * 2)) * 4096 + l31 * 8;
  const __bf16* Bp = Bt2 + ((size_t)(bx * 8 + nq * 2)) * 4096 + l31 * 8;

  v16f acc[2][2];
  #pragma unroll
  for (int a = 0; a < 2; ++a)
    #pragma unroll
    for (int b = 0; b < 2; ++b)
      #pragma unroll
      for (int r = 0; r < 16; ++r) acc[a][b][r] = 0.f;

  #pragma unroll
  for (int ks = 0; ks < 8; ++ks) {
    const int off = (ks * 2 + half) * 256;
    v8bf a0 = *(const v8bf*)(Ap + off);
    v8bf a1 = *(const v8bf*)(Ap + 4096 + off);
    v8bf b0 = *(const v8bf*)(Bp + off);
    v8bf b1 = *(const v8bf*)(Bp + 4096 + off);
    acc[0][0] = __builtin_amdgcn_mfma_f32_32x32x16_bf16(a0, b0, acc[0][0], 0, 0, 0);
    acc[0][1] = __builtin_amdgcn_mfma_f32_32x32x16_bf16(a0, b1, acc[0][1], 0, 0, 0);
    acc[1][0] = __builtin_amdgcn_mfma_f32_32x32x16_bf16(a1, b0, acc[1][0], 0, 0, 0);
    acc[1][1] = __builtin_amdgcn_mfma_f32_32x32x16_bf16(a1, b1, acc[1][1], 0, 0, 0);
  }

  // ---- P[p][c*32+d] = outer * rnorm, p = it*8 + jt ----
  #pragma unroll
  for (int ti = 0; ti < 2; ++ti) {
    #pragma unroll
    for (int tj = 0; tj < 2; ++tj) {
      const int it = mh * 2 + ti, jt = nq * 2 + tj;
      const int p = it * 8 + jt;
      const float rn = rnorm[(by * 4 + it) * NRES + bx * 8 + jt];
      #pragma unroll
      for (int r = 0; r < 16; ++r) {
        int cc = (r & 3) + 8 * (r >> 2) + 4 * half;
        Ps[p * 1032 + cc * 32 + l31] = (__bf16)(acc[ti][tj][r] * rn);
      }
    }
  }

  // ---- GEMM2 wot prefetch: issue BEFORE the barrier ----
  const int zg = w & 3, kh = w >> 2;
  const __bf16* wp = wot4 + ((size_t)((zg * 64 + kh * 32) * 64) + half * 32 + l31) * 8;
  v8bf wb[8];
  #pragma unroll
  for (int u = 0; u < 8; ++u)
    wb[u] = *(const v8bf*)(wp + u * 512);

  __syncthreads();

  // ---- GEMM2: 32x32x16 MFMA, K-split across wave pairs ----
  const __bf16* pp = Ps + l31 * 1032 + kh * 512 + half * 8;

  v16f c2;
  #pragma unroll
  for (int r = 0; r < 16; ++r) c2[r] = 0.f;

  #pragma unroll
  for (int g = 0; g < 4; ++g) {
    #pragma unroll
    for (int u = 0; u < 8; ++u) {
      const int kk = g * 8 + u;
      v8bf bb = wb[u];
      if (g < 3) wb[u] = *(const v8bf*)(wp + (kk + 8) * 512);
      v8bf aa = *(const v8bf*)(pp + kk * 16);
      c2 = __builtin_amdgcn_mfma_f32_32x32x16_bf16(aa, bb, c2, 0, 0, 0);
    }
  }

  // kh==1 partials -> separate bf16 region (no Ps aliasing, no extra barrier)
  if (kh == 1) {
    #pragma unroll
    for (int r = 0; r < 16; ++r) {
      int cc = (r & 3) + 8 * (r >> 2) + 4 * half;
      redb[zg * 1024 + cc * 32 + l31] = (__bf16)c2[r];
    }
  }
  __syncthreads();

  if (kh == 0) {
    const float bz = bo[zg * 32 + l31];
    #pragma unroll
    for (int r = 0; r < 16; ++r) {
      int cc = (r & 3) + 8 * (r >> 2) + 4 * half;   // = p row
      float v = c2[r] + (float)redb[zg * 1024 + cc * 32 + l31] + bz;
      int i = by * 4 + (cc >> 3), j = bx * 8 + (cc & 7);
      out[((size_t)i * NRES + j) * CZQ + zg * 32 + l31] = v;
    }
  }
}

extern "C" void kernel_launch(void* const* d_in, const int* in_sizes, int n_in,
                              void* d_out, int out_size, void* d_ws, size_t ws_size,
                              hipStream_t stream) {
  const float* msa  = (const float*)d_in[0];
  const float* mask = (const float*)d_in[1];
  const float* lnw  = (const float*)d_in[2];
  const float* lnb  = (const float*)d_in[3];
  const float* wl   = (const float*)d_in[4];
  const float* bl   = (const float*)d_in[5];
  const float* wr   = (const float*)d_in[6];
  const float* br   = (const float*)d_in[7];
  const float* wo   = (const float*)d_in[8];
  const float* bo   = (const float*)d_in[9];
  float* out = (float*)d_out;

  char* ws = (char*)d_ws;
  __bf16* At2   = (__bf16*)(ws);                    // 2 MB
  __bf16* Bt2   = (__bf16*)(ws + 2097152);          // 2 MB
  float*  rnorm = (float*)(ws + 4194304);           // 256 KB
  __bf16* wot4  = (__bf16*)(ws + 4456448);          // 256 KB

  fusedA_kernel<<<256, 512, 0, stream>>>(msa, lnw, lnb, wl, wr, mask, wo,
                                         bl, br, At2, Bt2, rnorm, wot4);
  outer_kernel<<<dim3(32, 64), 512, 0, stream>>>(At2, Bt2, rnorm, wot4, bo, out);
}